// Round 1
// baseline (188.335 us; speedup 1.0000x reference)
//
#include <hip/hip_runtime.h>

// DepthLossWithMask: loss = sum(|output - label0| * label1) / count(label0 != 0)
// N = 16*15*256*256 = 15,728,640 floats -> n4 = 3,932,160 float4.
//
// R2 finding: runtime invariant under full cache residency => latency-bound,
// not BW-bound. R3: atomic-free two-stage reduction (69us stage1).
// R4 (this version): stage1 was load-latency-serialized: VGPR_Count=52 proves
// the compiler couldn't cluster the 24 float4 loads/thread (96 VGPRs payload)
// and interleaved waitcnts instead (~0.45 KB in flight per wave vs 1+ KB
// needed). Fixes:
//   - n4 % (256*EPT) == 0 for this shape -> unchecked kernel specialization,
//     no per-k select/branch between loads (masked fallback kept).
//   - three clean unrolled load streams, compute only after all issued.
//   - __launch_bounds__(256, 4): 128-VGPR budget so all 24 loads cluster
//     back-to-back before a single waitcnt. 16 waves/CU x 24 KB in flight
//     >> ~10 KB/CU needed to hide ~900cy HBM latency at 6.3 TB/s.

#define REDUCE_THREADS 256
#define EPT 8   // float4 chunks per thread; block covers 256*8 = 2048 float4

struct Partial {
    float s;
    unsigned int c;
};

template <bool CHECK>
__global__ __launch_bounds__(REDUCE_THREADS, 4)
void depth_loss_stage1(const float4* __restrict__ out,
                       const float4* __restrict__ l0,
                       const float4* __restrict__ l1,
                       Partial* __restrict__ partials,
                       int n4) {
    const int base = blockIdx.x * (REDUCE_THREADS * EPT) + threadIdx.x;

    float4 o[EPT], a[EPT], w[EPT];
    if constexpr (CHECK) {
        #pragma unroll
        for (int k = 0; k < EPT; ++k) {
            int i = base + k * REDUCE_THREADS;
            bool ok = (i < n4);
            int j = ok ? i : 0;
            o[k] = out[j];
            a[k] = l0[j];
            w[k] = l1[j];
            if (!ok) {
                o[k] = make_float4(0.f, 0.f, 0.f, 0.f);
                a[k] = make_float4(0.f, 0.f, 0.f, 0.f);
                w[k] = make_float4(0.f, 0.f, 0.f, 0.f);
            }
        }
    } else {
        // No bounds check, no selects: pure load clusters. The compiler is
        // free (128-VGPR budget) to issue all 24 global_load_dwordx4
        // back-to-back and take one waitcnt before the FMA chain.
        #pragma unroll
        for (int k = 0; k < EPT; ++k) o[k] = out[base + k * REDUCE_THREADS];
        #pragma unroll
        for (int k = 0; k < EPT; ++k) a[k] = l0[base + k * REDUCE_THREADS];
        #pragma unroll
        for (int k = 0; k < EPT; ++k) w[k] = l1[base + k * REDUCE_THREADS];
    }

    float sum = 0.0f;
    unsigned int cnt = 0;
    #pragma unroll
    for (int k = 0; k < EPT; ++k) {
        sum += fabsf(o[k].x - a[k].x) * w[k].x;
        sum += fabsf(o[k].y - a[k].y) * w[k].y;
        sum += fabsf(o[k].z - a[k].z) * w[k].z;
        sum += fabsf(o[k].w - a[k].w) * w[k].w;
        cnt += (a[k].x != 0.0f) + (a[k].y != 0.0f) +
               (a[k].z != 0.0f) + (a[k].w != 0.0f);
    }

    // wave-64 butterfly reduce
    #pragma unroll
    for (int off = 32; off > 0; off >>= 1) {
        sum += __shfl_down(sum, off, 64);
        cnt += __shfl_down(cnt, off, 64);
    }

    __shared__ float        sv[REDUCE_THREADS / 64];
    __shared__ unsigned int sc[REDUCE_THREADS / 64];
    int lane = threadIdx.x & 63;
    int wid  = threadIdx.x >> 6;
    if (lane == 0) { sv[wid] = sum; sc[wid] = cnt; }
    __syncthreads();

    if (threadIdx.x == 0) {
        float bs = 0.0f;
        unsigned int bc = 0;
        #pragma unroll
        for (int i = 0; i < REDUCE_THREADS / 64; ++i) { bs += sv[i]; bc += sc[i]; }
        Partial p; p.s = bs; p.c = bc;
        partials[blockIdx.x] = p;   // plain 8B store, no contention
    }
}

__global__ __launch_bounds__(REDUCE_THREADS)
void depth_loss_stage2(const Partial* __restrict__ partials,
                       int nblocks,
                       float* __restrict__ out) {
    double sum = 0.0;
    unsigned int cnt = 0;
    for (int i = threadIdx.x; i < nblocks; i += REDUCE_THREADS) {
        Partial p = partials[i];
        sum += (double)p.s;
        cnt += p.c;
    }

    #pragma unroll
    for (int off = 32; off > 0; off >>= 1) {
        sum += __shfl_down(sum, off, 64);
        cnt += __shfl_down(cnt, off, 64);
    }

    __shared__ double       sv[REDUCE_THREADS / 64];
    __shared__ unsigned int sc[REDUCE_THREADS / 64];
    int lane = threadIdx.x & 63;
    int wid  = threadIdx.x >> 6;
    if (lane == 0) { sv[wid] = sum; sc[wid] = cnt; }
    __syncthreads();

    if (threadIdx.x == 0) {
        double bs = 0.0;
        unsigned int bc = 0;
        #pragma unroll
        for (int i = 0; i < REDUCE_THREADS / 64; ++i) { bs += sv[i]; bc += sc[i]; }
        out[0] = (bc == 0) ? 0.0f : (float)(bs / (double)bc);
    }
}

extern "C" void kernel_launch(void* const* d_in, const int* in_sizes, int n_in,
                              void* d_out, int out_size, void* d_ws, size_t ws_size,
                              hipStream_t stream) {
    const float* output = (const float*)d_in[0];
    const float* label0 = (const float*)d_in[1];
    const float* label1 = (const float*)d_in[2];
    int n = in_sizes[0];           // 15,728,640
    int n4 = n >> 2;               // 3,932,160 float4

    int per_block = REDUCE_THREADS * EPT;           // 2048 float4 per block
    int blocks = (n4 + per_block - 1) / per_block;  // 1920 (exact for this shape)

    Partial* partials = (Partial*)d_ws;             // 1920*8 = 15 KB, all written

    if ((n4 % per_block) == 0) {
        depth_loss_stage1<false><<<blocks, REDUCE_THREADS, 0, stream>>>(
            (const float4*)output, (const float4*)label0, (const float4*)label1,
            partials, n4);
    } else {
        depth_loss_stage1<true><<<blocks, REDUCE_THREADS, 0, stream>>>(
            (const float4*)output, (const float4*)label0, (const float4*)label1,
            partials, n4);
    }

    depth_loss_stage2<<<1, REDUCE_THREADS, 0, stream>>>(
        partials, blocks, (float*)d_out);
}

// Round 2
// 187.210 us; speedup vs baseline: 1.0060x; 1.0060x over previous
//
#include <hip/hip_runtime.h>

// DepthLossWithMask: loss = sum(|output - label0| * label1) / count(label0 != 0)
// N = 16*15*256*256 = 15,728,640 floats -> n4 = 3,932,160 float4.
//
// History:
//  R3: atomic-free two-stage reduction, stage1 ~70us.
//  R4 FAILED: __launch_bounds__(256,4) + separated load loops did NOT force
//     load clustering -- compiler re-interleaved (VGPR 52->36, dur unchanged).
//  R5 (this): Little's-law theory: read-only kernel at 2.7 TB/s effective with
//     neither HBM (17%) nor VALU (3.8%) saturated => outstanding-bytes limit.
//     Force MLP with a hard scheduler fence (__builtin_amdgcn_sched_barrier(0))
//     that the compiler cannot cross, holding 12 float4 loads (48 VGPRs) in
//     flight per thread. EPT 8->4 so the forced payload still fits ~8 waves/EU
//     (3840 blocks, 60 waves/CU of work -> smoother tail than 30).

#define REDUCE_THREADS 256
#define EPT 4   // float4 chunks per thread; block covers 256*4 = 1024 float4

struct Partial {
    float s;
    unsigned int c;
};

template <bool CHECK>
__global__ __launch_bounds__(REDUCE_THREADS)
void depth_loss_stage1(const float4* __restrict__ out,
                       const float4* __restrict__ l0,
                       const float4* __restrict__ l1,
                       Partial* __restrict__ partials,
                       int n4) {
    const int base = blockIdx.x * (REDUCE_THREADS * EPT) + threadIdx.x;

    float4 o[EPT], a[EPT], w[EPT];
    if constexpr (CHECK) {
        #pragma unroll
        for (int k = 0; k < EPT; ++k) {
            int i = base + k * REDUCE_THREADS;
            bool ok = (i < n4);
            int j = ok ? i : 0;
            o[k] = out[j];
            a[k] = l0[j];
            w[k] = l1[j];
            if (!ok) {
                o[k] = make_float4(0.f, 0.f, 0.f, 0.f);
                a[k] = make_float4(0.f, 0.f, 0.f, 0.f);
                w[k] = make_float4(0.f, 0.f, 0.f, 0.f);
            }
        }
    } else {
        // Issue all 12 global_load_dwordx4 back-to-back, then a hard
        // scheduling fence: nothing may be moved across sched_barrier(0),
        // so the compiler cannot sink loads into the compute and must keep
        // all 12 results (48 VGPRs) live -> 12 KB in flight per wave.
        #pragma unroll
        for (int k = 0; k < EPT; ++k) o[k] = out[base + k * REDUCE_THREADS];
        #pragma unroll
        for (int k = 0; k < EPT; ++k) a[k] = l0[base + k * REDUCE_THREADS];
        #pragma unroll
        for (int k = 0; k < EPT; ++k) w[k] = l1[base + k * REDUCE_THREADS];
        __builtin_amdgcn_sched_barrier(0);
    }

    float sum = 0.0f;
    unsigned int cnt = 0;
    #pragma unroll
    for (int k = 0; k < EPT; ++k) {
        sum += fabsf(o[k].x - a[k].x) * w[k].x;
        sum += fabsf(o[k].y - a[k].y) * w[k].y;
        sum += fabsf(o[k].z - a[k].z) * w[k].z;
        sum += fabsf(o[k].w - a[k].w) * w[k].w;
        cnt += (a[k].x != 0.0f) + (a[k].y != 0.0f) +
               (a[k].z != 0.0f) + (a[k].w != 0.0f);
    }

    // wave-64 butterfly reduce
    #pragma unroll
    for (int off = 32; off > 0; off >>= 1) {
        sum += __shfl_down(sum, off, 64);
        cnt += __shfl_down(cnt, off, 64);
    }

    __shared__ float        sv[REDUCE_THREADS / 64];
    __shared__ unsigned int sc[REDUCE_THREADS / 64];
    int lane = threadIdx.x & 63;
    int wid  = threadIdx.x >> 6;
    if (lane == 0) { sv[wid] = sum; sc[wid] = cnt; }
    __syncthreads();

    if (threadIdx.x == 0) {
        float bs = 0.0f;
        unsigned int bc = 0;
        #pragma unroll
        for (int i = 0; i < REDUCE_THREADS / 64; ++i) { bs += sv[i]; bc += sc[i]; }
        Partial p; p.s = bs; p.c = bc;
        partials[blockIdx.x] = p;   // plain 8B store, no contention
    }
}

__global__ __launch_bounds__(REDUCE_THREADS)
void depth_loss_stage2(const Partial* __restrict__ partials,
                       int nblocks,
                       float* __restrict__ out) {
    double sum = 0.0;
    unsigned int cnt = 0;
    for (int i = threadIdx.x; i < nblocks; i += REDUCE_THREADS) {
        Partial p = partials[i];
        sum += (double)p.s;
        cnt += p.c;
    }

    #pragma unroll
    for (int off = 32; off > 0; off >>= 1) {
        sum += __shfl_down(sum, off, 64);
        cnt += __shfl_down(cnt, off, 64);
    }

    __shared__ double       sv[REDUCE_THREADS / 64];
    __shared__ unsigned int sc[REDUCE_THREADS / 64];
    int lane = threadIdx.x & 63;
    int wid  = threadIdx.x >> 6;
    if (lane == 0) { sv[wid] = sum; sc[wid] = cnt; }
    __syncthreads();

    if (threadIdx.x == 0) {
        double bs = 0.0;
        unsigned int bc = 0;
        #pragma unroll
        for (int i = 0; i < REDUCE_THREADS / 64; ++i) { bs += sv[i]; bc += sc[i]; }
        out[0] = (bc == 0) ? 0.0f : (float)(bs / (double)bc);
    }
}

extern "C" void kernel_launch(void* const* d_in, const int* in_sizes, int n_in,
                              void* d_out, int out_size, void* d_ws, size_t ws_size,
                              hipStream_t stream) {
    const float* output = (const float*)d_in[0];
    const float* label0 = (const float*)d_in[1];
    const float* label1 = (const float*)d_in[2];
    int n = in_sizes[0];           // 15,728,640
    int n4 = n >> 2;               // 3,932,160 float4

    int per_block = REDUCE_THREADS * EPT;           // 1024 float4 per block
    int blocks = (n4 + per_block - 1) / per_block;  // 3840 (exact for this shape)

    Partial* partials = (Partial*)d_ws;             // 3840*8 = 30 KB, all written

    if ((n4 % per_block) == 0) {
        depth_loss_stage1<false><<<blocks, REDUCE_THREADS, 0, stream>>>(
            (const float4*)output, (const float4*)label0, (const float4*)label1,
            partials, n4);
    } else {
        depth_loss_stage1<true><<<blocks, REDUCE_THREADS, 0, stream>>>(
            (const float4*)output, (const float4*)label0, (const float4*)label1,
            partials, n4);
    }

    depth_loss_stage2<<<1, REDUCE_THREADS, 0, stream>>>(
        partials, blocks, (float*)d_out);
}